// Round 3
// baseline (211.966 us; speedup 1.0000x reference)
//
#include <hip/hip_runtime.h>

#define Bn 32
#define Wn 128
#define Sn 192
#define Dn 768
#define Hn 10
#define BHn 30
#define Cn 50
#define CAP 8
#define NEGV -1e30f
#define XPAD 4
#define NOCH 5

__device__ __forceinline__ float fsig(float x) {
    return __builtin_amdgcn_rcpf(1.0f + __expf(-x));
}
__device__ __forceinline__ float ftanh(float x) {
    return 1.0f - 2.0f * __builtin_amdgcn_rcpf(1.0f + __expf(2.0f * x));
}

// ---------------- zero counters ----------------
__global__ void k_zero(int* cnt) {
    int i = blockIdx.x * blockDim.x + threadIdx.x;
    if (i < Bn * Wn) cnt[i] = 0;
}

// ---------------- build token->word inverse lists ----------------
__global__ void k_lists(const int* __restrict__ b2t, int* cnt, int* lists) {
    int idx = blockIdx.x * blockDim.x + threadIdx.x;
    if (idx >= Bn * Sn) return;
    int b = idx / Sn;
    int w = b2t[idx];
    if (w < 0 || w >= Wn) return;
    int s = idx % Sn;
    int pos = atomicAdd(&cnt[b * Wn + w], 1);
    if (pos < CAP) lists[(b * Wn + w) * CAP + pos] = s;
}

// ---------------- fused mean(3 layers) + segment-mean ----------------
__global__ __launch_bounds__(192) void k_bertout(const float* __restrict__ hid,
                                                 const int* __restrict__ cnt,
                                                 const int* __restrict__ lists,
                                                 float* __restrict__ bert) {
    int bw = blockIdx.x;  // b*Wn + w
    int d4 = threadIdx.x; // 0..191 (float4 chunks of 768)
    int b = bw / Wn;
    int c = cnt[bw];
    int cc = c < CAP ? c : CAP;
    float4 acc = {0.f, 0.f, 0.f, 0.f};
    for (int tk = 0; tk < cc; ++tk) {
        int s = lists[bw * CAP + tk];
#pragma unroll
        for (int l = 0; l < 3; ++l) {
            const float4* p = (const float4*)(hid + ((size_t)(l * Bn + b) * (Sn + 1) + (s + 1)) * Dn) + d4;
            float4 v = *p;
            acc.x += v.x; acc.y += v.y; acc.z += v.z; acc.w += v.w;
        }
    }
    float inv = 1.0f / (3.0f * (float)(c > 0 ? c : 1));
    acc.x *= inv; acc.y *= inv; acc.z *= inv; acc.w *= inv;
    ((float4*)(bert + (size_t)bw * Dn))[d4] = acc;
}

// ---------------- input-gate projections xg = bert @ Wih^T + bih (both dirs) ----------------
__global__ __launch_bounds__(320) void k_xg(const float* __restrict__ bert,
                                            const float* __restrict__ Wf, const float* __restrict__ bf,
                                            const float* __restrict__ Wb, const float* __restrict__ bb,
                                            float* __restrict__ xg) {
    __shared__ float xl[16 * (Dn + XPAD)];
    int b = blockIdx.x >> 3;
    int tc = blockIdx.x & 7;
    int t0 = tc * 16;
    for (int idx = threadIdx.x; idx < 16 * (Dn / 4); idx += 320) {
        int r = idx / (Dn / 4), k4 = idx % (Dn / 4);
        float4 v = ((const float4*)(bert + (size_t)(b * Wn + t0 + r) * Dn))[k4];
        ((float4*)(xl + r * (Dn + XPAD)))[k4] = v;
    }
    __syncthreads();

    int g = threadIdx.x >> 2;  // 0..79
    int tq = threadIdx.x & 3;  // 0..3 -> 4 time rows each
    int dir = g / 40;
    int row = g % 40;
    const float4* wrow = (const float4*)((dir ? Wb : Wf) + row * Dn);
    float bias = (dir ? bb : bf)[row];
    const float4* x0 = (const float4*)(xl + (tq * 4 + 0) * (Dn + XPAD));
    const float4* x1 = (const float4*)(xl + (tq * 4 + 1) * (Dn + XPAD));
    const float4* x2 = (const float4*)(xl + (tq * 4 + 2) * (Dn + XPAD));
    const float4* x3 = (const float4*)(xl + (tq * 4 + 3) * (Dn + XPAD));
    float a0 = 0.f, a1 = 0.f, a2 = 0.f, a3 = 0.f;
    for (int k = 0; k < Dn / 4; ++k) {
        float4 w = wrow[k];
        float4 v0 = x0[k], v1 = x1[k], v2 = x2[k], v3 = x3[k];
        a0 += w.x * v0.x + w.y * v0.y + w.z * v0.z + w.w * v0.w;
        a1 += w.x * v1.x + w.y * v1.y + w.z * v1.z + w.w * v1.w;
        a2 += w.x * v2.x + w.y * v2.y + w.z * v2.z + w.w * v2.w;
        a3 += w.x * v3.x + w.y * v3.y + w.z * v3.z + w.w * v3.w;
    }
    size_t base = (size_t)(dir * Bn + b) * Wn + t0 + tq * 4;
    xg[(base + 0) * 40 + row] = a0 + bias;
    xg[(base + 1) * 40 + row] = a1 + bias;
    xg[(base + 2) * 40 + row] = a2 + bias;
    xg[(base + 3) * 40 + row] = a3 + bias;
}

// ---------------- LSTM scan: LDS-staged xg, wave-local shuffle recurrence ----------------
__global__ __launch_bounds__(64) void k_lstm(const float* __restrict__ xg,
                                             const float* __restrict__ Whh_f, const float* __restrict__ bhh_f,
                                             const float* __restrict__ Whh_b, const float* __restrict__ bhh_b,
                                             float* __restrict__ hs) {
    __shared__ float xl[4 * 5128]; // 4 seqs x (128*40) padded by 8
    int lane = threadIdx.x;
    int grp = lane >> 4;
    int j = lane & 15;
    int jj = j < Hn ? j : (Hn - 1);
    int seq = blockIdx.x * 4 + grp;
    int dir = seq >> 5; // uniform per block
    int b = seq & 31;

    // stage all 4 sequences' xg into LDS (coalesced float4)
    for (int s = 0; s < 4; ++s) {
        int sq = blockIdx.x * 4 + s;
        int d = sq >> 5, bb2 = sq & 31;
        const float4* src = (const float4*)(xg + (size_t)(d * Bn + bb2) * Wn * 40);
        float4* dst = (float4*)(xl + s * 5128);
        for (int idx = lane; idx < 1280; idx += 64) dst[idx] = src[idx];
    }

    const float* Whh = dir ? Whh_b : Whh_f;
    const float* bhh = dir ? bhh_b : bhh_f;
    float wi[Hn], wf[Hn], wg[Hn], wo[Hn];
#pragma unroll
    for (int k = 0; k < Hn; ++k) {
        wi[k] = Whh[(0 * Hn + jj) * Hn + k];
        wf[k] = Whh[(1 * Hn + jj) * Hn + k];
        wg[k] = Whh[(2 * Hn + jj) * Hn + k];
        wo[k] = Whh[(3 * Hn + jj) * Hn + k];
    }
    float bi = bhh[jj], bf_ = bhh[Hn + jj], bg = bhh[2 * Hn + jj], bo = bhh[3 * Hn + jj];

    __syncthreads();

    const float* xs = xl + grp * 5128;
    float* hbase = hs + (size_t)(dir * Bn + b) * Wn * Hn;

    float h = 0.f, c = 0.f;
    int dt = dir ? -1 : 1;
    int t = dir ? (Wn - 1) : 0;
    float xi = xs[t * 40 + jj], xf = xs[t * 40 + 10 + jj];
    float xgg = xs[t * 40 + 20 + jj], xo = xs[t * 40 + 30 + jj];

    for (int step = 0; step < Wn; ++step) {
        int tn = t + dt;
        float nxi = 0.f, nxf = 0.f, nxg = 0.f, nxo = 0.f;
        if (step + 1 < Wn) { // prefetch next step from LDS (independent)
            const float* xr = xs + tn * 40;
            nxi = xr[jj]; nxf = xr[10 + jj]; nxg = xr[20 + jj]; nxo = xr[30 + jj];
        }
        float hv[Hn];
#pragma unroll
        for (int k = 0; k < Hn; ++k) hv[k] = __shfl(h, k, 16);
        float gi = xi + bi, gf = xf + bf_, gg = xgg + bg, go = xo + bo;
#pragma unroll
        for (int k = 0; k < Hn; ++k) {
            gi += wi[k] * hv[k];
            gf += wf[k] * hv[k];
            gg += wg[k] * hv[k];
            go += wo[k] * hv[k];
        }
        c = fsig(gf) * c + fsig(gi) * ftanh(gg);
        h = fsig(go) * ftanh(c);
        if (j < Hn) hbase[t * Hn + j] = h;
        xi = nxi; xf = nxf; xgg = nxg; xo = nxo;
        t = tn;
    }
}

// ---------------- MLP heads: 4x relu(x@W+b) with appended 1; also writes padded dr-h1 ----------------
__global__ __launch_bounds__(128) void k_mlp(const float* __restrict__ hs,
                                             const float* __restrict__ uW1, const float* __restrict__ ub1,
                                             const float* __restrict__ uW2, const float* __restrict__ ub2,
                                             const float* __restrict__ dW1, const float* __restrict__ db1,
                                             const float* __restrict__ dW2, const float* __restrict__ db2,
                                             float* __restrict__ harr, float* __restrict__ h1g) {
    int bt = blockIdx.x; // b*Wn + t
    int b = bt / Wn, t = bt % Wn;
    __shared__ float x[20];
    int tid = threadIdx.x;
    if (tid < 20) {
        x[tid] = (tid < Hn) ? hs[((size_t)(0 * Bn + b) * Wn + t) * Hn + tid]
                            : hs[((size_t)(1 * Bn + b) * Wn + t) * Hn + (tid - Hn)];
    }
    __syncthreads();
    if (tid == 124) h1g[(size_t)bt * 32 + 31] = 0.f; // pad
    if (tid >= 124) return;
    int which = tid / 31, k = tid % 31;
    float v;
    if (k == 30) {
        v = 1.0f;
    } else {
        const float* Wm;
        const float* bv;
        if (which == 0) { Wm = uW1; bv = ub1; }
        else if (which == 1) { Wm = uW2; bv = ub2; }
        else if (which == 2) { Wm = dW1; bv = db1; }
        else { Wm = dW2; bv = db2; }
        float a = bv[k];
#pragma unroll
        for (int d = 0; d < 20; ++d) a += x[d] * Wm[d * BHn + k];
        v = a > 0.f ? a : 0.f;
    }
    harr[((size_t)which * Bn * Wn + bt) * 31 + k] = v;
    if (which == 2) h1g[(size_t)bt * 32 + k] = v;
}

// ---------------- gather dr-h2 rows at j=head into padded array ----------------
__global__ __launch_bounds__(256) void k_gather(const float* __restrict__ harr,
                                                const int* __restrict__ heads,
                                                float* __restrict__ h2g) {
    int idx = blockIdx.x * 256 + threadIdx.x; // n*8 + q
    int n = idx >> 3, q = idx & 7;
    int b = n >> 7;
    int jh = heads[n];
    if (jh < 0 || jh >= Wn) jh = 0;
    const float* src = harr + ((size_t)3 * Bn * Wn + b * Wn + jh) * 31;
    float4 v;
    float tmp[4];
#pragma unroll
    for (int e = 0; e < 4; ++e) {
        int k = q * 4 + e;
        tmp[e] = (k < 31) ? src[k] : 0.f;
    }
    v.x = tmp[0]; v.y = tmp[1]; v.z = tmp[2]; v.w = tmp[3];
    ((float4*)(h2g + (size_t)n * 32))[q] = v;
}

// ---------------- unlabeled: single-wave per (b,i), shuffle softmax ----------------
__global__ __launch_bounds__(64) void k_unlab(const float* __restrict__ harr,
                                              const float* __restrict__ U0, const float* __restrict__ ubias,
                                              const int* __restrict__ heads, const unsigned char* __restrict__ masks,
                                              float* __restrict__ un_part) {
    int b = blockIdx.x / (Wn - 1);
    int i = 1 + blockIdx.x % (Wn - 1);
    const float* h2a = harr + (size_t)Bn * Wn * 31;
    __shared__ float h2s[Wn * 31];
    __shared__ float U0l[964];
    __shared__ float tgl[31];
    int l = threadIdx.x;
    const float4* src = (const float4*)(h2a + (size_t)b * Wn * 31);
    for (int idx = l; idx < Wn * 31 / 4; idx += 64) ((float4*)h2s)[idx] = src[idx];
    for (int idx = l; idx < 240; idx += 64) ((float4*)U0l)[idx] = ((const float4*)U0)[idx];
    if (l == 0) U0l[960] = U0[960];
    __syncthreads();
    if (l < 31) {
        const float* h1row = harr + ((size_t)b * Wn + i) * 31;
        float a = 0.f;
        for (int h = 0; h < 31; ++h) a += h1row[h] * U0l[h * 31 + l];
        tgl[l] = a;
    }
    __syncthreads();
    float ub = ubias[0];
    float s0 = ub, s1 = ub;
    const float* r0 = h2s + l * 31;
    const float* r1 = h2s + (l + 64) * 31;
#pragma unroll
    for (int g = 0; g < 31; ++g) {
        float tv = tgl[g];
        s0 += tv * r0[g];
        s1 += tv * r1[g];
    }
    if (l == i) s0 = NEGV;
    if (l + 64 == i) s1 = NEGV;
    float m = fmaxf(s0, s1);
#pragma unroll
    for (int off = 1; off < 64; off <<= 1) m = fmaxf(m, __shfl_xor(m, off));
    float e = __expf(s0 - m) + __expf(s1 - m);
#pragma unroll
    for (int off = 1; off < 64; off <<= 1) e += __shfl_xor(e, off);
    float lse = m + __logf(e);
    int head = heads[b * Wn + i]; // uniform
    float v = (head < 64) ? s0 : s1;
    float sh = __shfl(v, head & 63);
    if (l == 0) un_part[blockIdx.x] = masks[b * Wn + i] ? 0.f : -(sh - lse);
}

// ---------------- deprel scores: reg-resident h1/h2, broadcast-LDS U ----------------
__global__ __launch_bounds__(64) void k_drscore(const float* __restrict__ h1g,
                                                const float* __restrict__ h2g,
                                                const float* __restrict__ U, const float* __restrict__ dbias,
                                                float* __restrict__ sc) {
    int nc = blockIdx.x & 63;  // 64 n-chunks of 64
    int oc = blockIdx.x >> 6;  // 10 o-chunks of 5
    int o0 = oc * NOCH;
    __shared__ float Ul[NOCH][31][32];
    __shared__ float h1l[64][33];
    int tid = threadIdx.x;
    for (int idx = tid; idx < NOCH * 31 * 32; idx += 64) {
        int o = idx / 992, r = idx - o * 992;
        int h = r >> 5, g = r & 31;
        Ul[o][h][g] = (g < 31) ? U[(size_t)(o0 + o) * 961 + h * 31 + g] : 0.f;
    }
    for (int idx = tid; idx < 64 * 32; idx += 64) {
        int r = idx >> 5, k = idx & 31;
        h1l[r][k] = h1g[(size_t)(nc * 64) * 32 + idx];
    }
    int n = nc * 64 + tid;
    float h2r[32];
    {
        const float4* p = (const float4*)(h2g + (size_t)n * 32);
#pragma unroll
        for (int q = 0; q < 8; ++q) {
            float4 v = p[q];
            h2r[4 * q + 0] = v.x; h2r[4 * q + 1] = v.y;
            h2r[4 * q + 2] = v.z; h2r[4 * q + 3] = v.w;
        }
    }
    __syncthreads();
    float a0 = 0.f, a1 = 0.f, a2 = 0.f, a3 = 0.f, a4 = 0.f;
    for (int h = 0; h < 31; ++h) {
        float t0 = 0.f, t1 = 0.f, t2 = 0.f, t3 = 0.f, t4 = 0.f;
#pragma unroll
        for (int g = 0; g < 32; ++g) {
            float x = h2r[g];
            t0 += Ul[0][h][g] * x;
            t1 += Ul[1][h][g] * x;
            t2 += Ul[2][h][g] * x;
            t3 += Ul[3][h][g] * x;
            t4 += Ul[4][h][g] * x;
        }
        float a = h1l[tid][h];
        a0 += a * t0; a1 += a * t1; a2 += a * t2; a3 += a * t3; a4 += a * t4;
    }
    float* out = sc + (size_t)n * Cn + o0;
    out[0] = a0 + dbias[o0 + 0];
    out[1] = a1 + dbias[o0 + 1];
    out[2] = a2 + dbias[o0 + 2];
    out[3] = a3 + dbias[o0 + 3];
    out[4] = a4 + dbias[o0 + 4];
}

// ---------------- deprel CE: one wave per n ----------------
__global__ __launch_bounds__(256) void k_drce(const float* __restrict__ sc,
                                              const int* __restrict__ dep_rels,
                                              float* __restrict__ drce_part) {
    int w = threadIdx.x >> 6;
    int l = threadIdx.x & 63;
    int n = blockIdx.x * 4 + w;
    float v = (l < Cn) ? sc[(size_t)n * Cn + l] : NEGV;
    float m = v;
#pragma unroll
    for (int off = 1; off < 64; off <<= 1) m = fmaxf(m, __shfl_xor(m, off));
    float e = (l < Cn) ? __expf(v - m) : 0.f;
#pragma unroll
    for (int off = 1; off < 64; off <<= 1) e += __shfl_xor(e, off);
    float lse = m + __logf(e);
    int r = dep_rels[n]; // uniform per wave
    float vr = __shfl(v, r);
    if (l == 0) drce_part[n] = (r != 0 && r < Cn) ? -(vr - lse) : 0.f;
}

// ---------------- final reduce ----------------
__global__ __launch_bounds__(256) void k_final(const float* __restrict__ un_part,
                                               const float* __restrict__ drce_part,
                                               float* __restrict__ out) {
    __shared__ float red[256];
    int tid = threadIdx.x;
    float a = 0.f;
    for (int idx = tid; idx < Bn * (Wn - 1); idx += 256) a += un_part[idx];
    for (int idx = tid; idx < Bn * Wn; idx += 256) a += drce_part[idx];
    red[tid] = a;
    __syncthreads();
    for (int off = 128; off > 0; off >>= 1) {
        if (tid < off) red[tid] += red[tid + off];
        __syncthreads();
    }
    if (tid == 0) out[0] = red[0];
}

extern "C" void kernel_launch(void* const* d_in, const int* in_sizes, int n_in,
                              void* d_out, int out_size, void* d_ws, size_t ws_size,
                              hipStream_t stream) {
    const float* hiddens = (const float*)d_in[0];
    const int* b2t = (const int*)d_in[1];
    const int* heads = (const int*)d_in[2];
    const int* dep_rels = (const int*)d_in[3];
    const unsigned char* masks = (const unsigned char*)d_in[4];
    const float* Wih_f = (const float*)d_in[6];
    const float* Whh_f = (const float*)d_in[7];
    const float* bih_f = (const float*)d_in[8];
    const float* bhh_f = (const float*)d_in[9];
    const float* Wih_b = (const float*)d_in[10];
    const float* Whh_b = (const float*)d_in[11];
    const float* bih_b = (const float*)d_in[12];
    const float* bhh_b = (const float*)d_in[13];
    const float* un_W1 = (const float*)d_in[14];
    const float* un_b1 = (const float*)d_in[15];
    const float* un_W2 = (const float*)d_in[16];
    const float* un_b2 = (const float*)d_in[17];
    const float* un_U  = (const float*)d_in[18];
    const float* un_bias = (const float*)d_in[19];
    const float* dr_W1 = (const float*)d_in[20];
    const float* dr_b1 = (const float*)d_in[21];
    const float* dr_W2 = (const float*)d_in[22];
    const float* dr_b2 = (const float*)d_in[23];
    const float* dr_U  = (const float*)d_in[24];
    const float* dr_bias = (const float*)d_in[25];

    char* p = (char*)d_ws;
    float* un_part = (float*)p;   p += (size_t)4096 * 4;
    float* drce_part = (float*)p; p += (size_t)4096 * 4;
    int* cnt = (int*)p;           p += (size_t)Bn * Wn * 4;
    int* lists = (int*)p;         p += (size_t)Bn * Wn * CAP * 4;
    float* bert = (float*)p;      p += (size_t)Bn * Wn * Dn * 4;
    float* xg = (float*)p;        p += (size_t)2 * Bn * Wn * 40 * 4;
    float* hs = (float*)p;        p += (size_t)2 * Bn * Wn * Hn * 4;
    float* harr = (float*)p;      p += (size_t)4 * Bn * Wn * 31 * 4;
    float* h1g = (float*)p;       p += (size_t)Bn * Wn * 32 * 4;
    float* h2g = (float*)p;       p += (size_t)Bn * Wn * 32 * 4;
    float* sc = (float*)p;        p += (size_t)Bn * Wn * Cn * 4;

    k_zero<<<(Bn * Wn + 255) / 256, 256, 0, stream>>>(cnt);
    k_lists<<<(Bn * Sn + 255) / 256, 256, 0, stream>>>(b2t, cnt, lists);
    k_bertout<<<Bn * Wn, 192, 0, stream>>>(hiddens, cnt, lists, bert);
    k_xg<<<Bn * 8, 320, 0, stream>>>(bert, Wih_f, bih_f, Wih_b, bih_b, xg);
    k_lstm<<<16, 64, 0, stream>>>(xg, Whh_f, bhh_f, Whh_b, bhh_b, hs);
    k_mlp<<<Bn * Wn, 128, 0, stream>>>(hs, un_W1, un_b1, un_W2, un_b2,
                                       dr_W1, dr_b1, dr_W2, dr_b2, harr, h1g);
    k_gather<<<Bn * Wn * 8 / 256, 256, 0, stream>>>(harr, heads, h2g);
    k_unlab<<<Bn * (Wn - 1), 64, 0, stream>>>(harr, un_U, un_bias, heads, masks, un_part);
    k_drscore<<<640, 64, 0, stream>>>(h1g, h2g, dr_U, dr_bias, sc);
    k_drce<<<Bn * Wn / 4, 256, 0, stream>>>(sc, dep_rels, drce_part);
    k_final<<<1, 256, 0, stream>>>(un_part, drce_part, (float*)d_out);
}

// Round 4
// 163.609 us; speedup vs baseline: 1.2956x; 1.2956x over previous
//
#include <hip/hip_runtime.h>

#define Bn 32
#define Wn 128
#define Sn 192
#define Dn 768
#define Hn 10
#define BHn 30
#define Cn 50
#define CAP 8
#define NEGV -1e30f
#define XPAD 4

__device__ __forceinline__ float fsig(float x) {
    return __builtin_amdgcn_rcpf(1.0f + __expf(-x));
}
__device__ __forceinline__ float ftanh(float x) {
    return 1.0f - 2.0f * __builtin_amdgcn_rcpf(1.0f + __expf(2.0f * x));
}

// ---------------- zero counters ----------------
__global__ void k_zero(int* cnt) {
    int i = blockIdx.x * blockDim.x + threadIdx.x;
    if (i < Bn * Wn) cnt[i] = 0;
}

// ---------------- build token->word inverse lists ----------------
__global__ void k_lists(const int* __restrict__ b2t, int* cnt, int* lists) {
    int idx = blockIdx.x * blockDim.x + threadIdx.x;
    if (idx >= Bn * Sn) return;
    int b = idx / Sn;
    int w = b2t[idx];
    if (w < 0 || w >= Wn) return;
    int s = idx % Sn;
    int pos = atomicAdd(&cnt[b * Wn + w], 1);
    if (pos < CAP) lists[(b * Wn + w) * CAP + pos] = s;
}

// ---------------- fused mean(3 layers) + segment-mean ----------------
__global__ __launch_bounds__(192) void k_bertout(const float* __restrict__ hid,
                                                 const int* __restrict__ cnt,
                                                 const int* __restrict__ lists,
                                                 float* __restrict__ bert) {
    int bw = blockIdx.x;  // b*Wn + w
    int d4 = threadIdx.x; // 0..191 (float4 chunks of 768)
    int b = bw / Wn;
    int c = cnt[bw];
    int cc = c < CAP ? c : CAP;
    float4 acc = {0.f, 0.f, 0.f, 0.f};
    for (int tk = 0; tk < cc; ++tk) {
        int s = lists[bw * CAP + tk];
#pragma unroll
        for (int l = 0; l < 3; ++l) {
            const float4* p = (const float4*)(hid + ((size_t)(l * Bn + b) * (Sn + 1) + (s + 1)) * Dn) + d4;
            float4 v = *p;
            acc.x += v.x; acc.y += v.y; acc.z += v.z; acc.w += v.w;
        }
    }
    float inv = 1.0f / (3.0f * (float)(c > 0 ? c : 1));
    acc.x *= inv; acc.y *= inv; acc.z *= inv; acc.w *= inv;
    ((float4*)(bert + (size_t)bw * Dn))[d4] = acc;
}

// ---------------- input-gate projections xg = bert @ Wih^T + bih (both dirs) ----------------
__global__ __launch_bounds__(320) void k_xg(const float* __restrict__ bert,
                                            const float* __restrict__ Wf, const float* __restrict__ bf,
                                            const float* __restrict__ Wb, const float* __restrict__ bb,
                                            float* __restrict__ xg) {
    __shared__ float xl[16 * (Dn + XPAD)];
    int b = blockIdx.x >> 3;
    int tc = blockIdx.x & 7;
    int t0 = tc * 16;
    for (int idx = threadIdx.x; idx < 16 * (Dn / 4); idx += 320) {
        int r = idx / (Dn / 4), k4 = idx % (Dn / 4);
        float4 v = ((const float4*)(bert + (size_t)(b * Wn + t0 + r) * Dn))[k4];
        ((float4*)(xl + r * (Dn + XPAD)))[k4] = v;
    }
    __syncthreads();

    int g = threadIdx.x >> 2;  // 0..79
    int tq = threadIdx.x & 3;  // 0..3 -> 4 time rows each
    int dir = g / 40;
    int row = g % 40;
    const float4* wrow = (const float4*)((dir ? Wb : Wf) + row * Dn);
    float bias = (dir ? bb : bf)[row];
    const float4* x0 = (const float4*)(xl + (tq * 4 + 0) * (Dn + XPAD));
    const float4* x1 = (const float4*)(xl + (tq * 4 + 1) * (Dn + XPAD));
    const float4* x2 = (const float4*)(xl + (tq * 4 + 2) * (Dn + XPAD));
    const float4* x3 = (const float4*)(xl + (tq * 4 + 3) * (Dn + XPAD));
    float a0 = 0.f, a1 = 0.f, a2 = 0.f, a3 = 0.f;
    for (int k = 0; k < Dn / 4; ++k) {
        float4 w = wrow[k];
        float4 v0 = x0[k], v1 = x1[k], v2 = x2[k], v3 = x3[k];
        a0 += w.x * v0.x + w.y * v0.y + w.z * v0.z + w.w * v0.w;
        a1 += w.x * v1.x + w.y * v1.y + w.z * v1.z + w.w * v1.w;
        a2 += w.x * v2.x + w.y * v2.y + w.z * v2.z + w.w * v2.w;
        a3 += w.x * v3.x + w.y * v3.y + w.z * v3.z + w.w * v3.w;
    }
    size_t base = (size_t)(dir * Bn + b) * Wn + t0 + tq * 4;
    xg[(base + 0) * 40 + row] = a0 + bias;
    xg[(base + 1) * 40 + row] = a1 + bias;
    xg[(base + 2) * 40 + row] = a2 + bias;
    xg[(base + 3) * 40 + row] = a3 + bias;
}

// ---------------- LSTM scan: LDS-staged xg, wave-local shuffle recurrence ----------------
__global__ __launch_bounds__(64) void k_lstm(const float* __restrict__ xg,
                                             const float* __restrict__ Whh_f, const float* __restrict__ bhh_f,
                                             const float* __restrict__ Whh_b, const float* __restrict__ bhh_b,
                                             float* __restrict__ hs) {
    __shared__ float xl[4 * 5128]; // 4 seqs x (128*40) padded by 8
    int lane = threadIdx.x;
    int grp = lane >> 4;
    int j = lane & 15;
    int jj = j < Hn ? j : (Hn - 1);
    int seq = blockIdx.x * 4 + grp;
    int dir = seq >> 5; // uniform per block
    int b = seq & 31;

    for (int s = 0; s < 4; ++s) {
        int sq = blockIdx.x * 4 + s;
        int d = sq >> 5, bb2 = sq & 31;
        const float4* src = (const float4*)(xg + (size_t)(d * Bn + bb2) * Wn * 40);
        float4* dst = (float4*)(xl + s * 5128);
        for (int idx = lane; idx < 1280; idx += 64) dst[idx] = src[idx];
    }

    const float* Whh = dir ? Whh_b : Whh_f;
    const float* bhh = dir ? bhh_b : bhh_f;
    float wi[Hn], wf[Hn], wg[Hn], wo[Hn];
#pragma unroll
    for (int k = 0; k < Hn; ++k) {
        wi[k] = Whh[(0 * Hn + jj) * Hn + k];
        wf[k] = Whh[(1 * Hn + jj) * Hn + k];
        wg[k] = Whh[(2 * Hn + jj) * Hn + k];
        wo[k] = Whh[(3 * Hn + jj) * Hn + k];
    }
    float bi = bhh[jj], bf_ = bhh[Hn + jj], bg = bhh[2 * Hn + jj], bo = bhh[3 * Hn + jj];

    __syncthreads();

    const float* xs = xl + grp * 5128;
    float* hbase = hs + (size_t)(dir * Bn + b) * Wn * Hn;

    float h = 0.f, c = 0.f;
    int dt = dir ? -1 : 1;
    int t = dir ? (Wn - 1) : 0;
    float xi = xs[t * 40 + jj], xf = xs[t * 40 + 10 + jj];
    float xgg = xs[t * 40 + 20 + jj], xo = xs[t * 40 + 30 + jj];

    for (int step = 0; step < Wn; ++step) {
        int tn = t + dt;
        float nxi = 0.f, nxf = 0.f, nxg = 0.f, nxo = 0.f;
        if (step + 1 < Wn) {
            const float* xr = xs + tn * 40;
            nxi = xr[jj]; nxf = xr[10 + jj]; nxg = xr[20 + jj]; nxo = xr[30 + jj];
        }
        float hv[Hn];
#pragma unroll
        for (int k = 0; k < Hn; ++k) hv[k] = __shfl(h, k, 16);
        float gi = xi + bi, gf = xf + bf_, gg = xgg + bg, go = xo + bo;
#pragma unroll
        for (int k = 0; k < Hn; ++k) {
            gi += wi[k] * hv[k];
            gf += wf[k] * hv[k];
            gg += wg[k] * hv[k];
            go += wo[k] * hv[k];
        }
        c = fsig(gf) * c + fsig(gi) * ftanh(gg);
        h = fsig(go) * ftanh(c);
        if (j < Hn) hbase[t * Hn + j] = h;
        xi = nxi; xf = nxf; xgg = nxg; xo = nxo;
        t = tn;
    }
}

// ---------------- MLP heads: 4x relu(x@W+b) with appended 1; also writes padded dr-h1 ----------------
__global__ __launch_bounds__(128) void k_mlp(const float* __restrict__ hs,
                                             const float* __restrict__ uW1, const float* __restrict__ ub1,
                                             const float* __restrict__ uW2, const float* __restrict__ ub2,
                                             const float* __restrict__ dW1, const float* __restrict__ db1,
                                             const float* __restrict__ dW2, const float* __restrict__ db2,
                                             float* __restrict__ harr, float* __restrict__ h1g) {
    int bt = blockIdx.x; // b*Wn + t
    int b = bt / Wn, t = bt % Wn;
    __shared__ float x[20];
    int tid = threadIdx.x;
    if (tid < 20) {
        x[tid] = (tid < Hn) ? hs[((size_t)(0 * Bn + b) * Wn + t) * Hn + tid]
                            : hs[((size_t)(1 * Bn + b) * Wn + t) * Hn + (tid - Hn)];
    }
    __syncthreads();
    if (tid == 124) h1g[(size_t)bt * 32 + 31] = 0.f; // pad
    if (tid >= 124) return;
    int which = tid / 31, k = tid % 31;
    float v;
    if (k == 30) {
        v = 1.0f;
    } else {
        const float* Wm;
        const float* bv;
        if (which == 0) { Wm = uW1; bv = ub1; }
        else if (which == 1) { Wm = uW2; bv = ub2; }
        else if (which == 2) { Wm = dW1; bv = db1; }
        else { Wm = dW2; bv = db2; }
        float a = bv[k];
#pragma unroll
        for (int d = 0; d < 20; ++d) a += x[d] * Wm[d * BHn + k];
        v = a > 0.f ? a : 0.f;
    }
    harr[((size_t)which * Bn * Wn + bt) * 31 + k] = v;
    if (which == 2) h1g[(size_t)bt * 32 + k] = v;
}

// ---------------- gather dr-h2 rows at j=head into padded array ----------------
__global__ __launch_bounds__(256) void k_gather(const float* __restrict__ harr,
                                                const int* __restrict__ heads,
                                                float* __restrict__ h2g) {
    int idx = blockIdx.x * 256 + threadIdx.x; // n*8 + q
    int n = idx >> 3, q = idx & 7;
    int b = n >> 7;
    int jh = heads[n];
    if (jh < 0 || jh >= Wn) jh = 0;
    const float* src = harr + ((size_t)3 * Bn * Wn + b * Wn + jh) * 31;
    float4 v;
    float tmp[4];
#pragma unroll
    for (int e = 0; e < 4; ++e) {
        int k = q * 4 + e;
        tmp[e] = (k < 31) ? src[k] : 0.f;
    }
    v.x = tmp[0]; v.y = tmp[1]; v.z = tmp[2]; v.w = tmp[3];
    ((float4*)(h2g + (size_t)n * 32))[q] = v;
}

// ---------------- unlabeled: single-wave per (b,i), shuffle softmax ----------------
__global__ __launch_bounds__(64) void k_unlab(const float* __restrict__ harr,
                                              const float* __restrict__ U0, const float* __restrict__ ubias,
                                              const int* __restrict__ heads, const unsigned char* __restrict__ masks,
                                              float* __restrict__ un_part) {
    int b = blockIdx.x / (Wn - 1);
    int i = 1 + blockIdx.x % (Wn - 1);
    const float* h2a = harr + (size_t)Bn * Wn * 31;
    __shared__ float h2s[Wn * 31];
    __shared__ float U0l[964];
    __shared__ float tgl[31];
    int l = threadIdx.x;
    const float4* src = (const float4*)(h2a + (size_t)b * Wn * 31);
    for (int idx = l; idx < Wn * 31 / 4; idx += 64) ((float4*)h2s)[idx] = src[idx];
    for (int idx = l; idx < 240; idx += 64) ((float4*)U0l)[idx] = ((const float4*)U0)[idx];
    if (l == 0) U0l[960] = U0[960];
    __syncthreads();
    if (l < 31) {
        const float* h1row = harr + ((size_t)b * Wn + i) * 31;
        float a = 0.f;
        for (int h = 0; h < 31; ++h) a += h1row[h] * U0l[h * 31 + l];
        tgl[l] = a;
    }
    __syncthreads();
    float ub = ubias[0];
    float s0 = ub, s1 = ub;
    const float* r0 = h2s + l * 31;
    const float* r1 = h2s + (l + 64) * 31;
#pragma unroll
    for (int g = 0; g < 31; ++g) {
        float tv = tgl[g];
        s0 += tv * r0[g];
        s1 += tv * r1[g];
    }
    if (l == i) s0 = NEGV;
    if (l + 64 == i) s1 = NEGV;
    float m = fmaxf(s0, s1);
#pragma unroll
    for (int off = 1; off < 64; off <<= 1) m = fmaxf(m, __shfl_xor(m, off));
    float e = __expf(s0 - m) + __expf(s1 - m);
#pragma unroll
    for (int off = 1; off < 64; off <<= 1) e += __shfl_xor(e, off);
    float lse = m + __logf(e);
    int head = heads[b * Wn + i]; // uniform
    float v = (head < 64) ? s0 : s1;
    float sh = __shfl(v, head & 63);
    if (l == 0) un_part[blockIdx.x] = masks[b * Wn + i] ? 0.f : -(sh - lse);
}

// ---------------- deprel scores: thread=(n,o), U broadcast from LDS, h1/h2 in regs ----------------
// grid: 64 n-chunks x 13 o-quads; block 256 = 4 waves; wave w -> o = oq*4+w, lane -> n
__global__ __launch_bounds__(256) void k_drscore(const float* __restrict__ h1g,
                                                 const float* __restrict__ h2g,
                                                 const float* __restrict__ U, const float* __restrict__ dbias,
                                                 float* __restrict__ sc) {
    int nc = blockIdx.x & 63;
    int oq = blockIdx.x >> 6; // 0..12
    __shared__ float Ul[4][992]; // row stride 32 per h (aligned b128)
    int tid = threadIdx.x;
    for (int idx = tid; idx < 4 * 992; idx += 256) {
        int o = idx / 992, r = idx - o * 992;
        int h = r >> 5, g = r & 31;
        int oo = oq * 4 + o; if (oo >= Cn) oo = Cn - 1;
        Ul[o][r] = (g < 31) ? U[(size_t)oo * 961 + h * 31 + g] : 0.f;
    }
    int w = tid >> 6, lane = tid & 63;
    int o = oq * 4 + w;
    int n = nc * 64 + lane;
    float h2r[32];
    {
        const float4* p = (const float4*)(h2g + (size_t)n * 32);
#pragma unroll
        for (int q = 0; q < 8; ++q) {
            float4 v = p[q];
            h2r[4 * q + 0] = v.x; h2r[4 * q + 1] = v.y;
            h2r[4 * q + 2] = v.z; h2r[4 * q + 3] = v.w;
        }
    }
    float h1r[32];
    {
        const float4* p = (const float4*)(h1g + (size_t)n * 32);
#pragma unroll
        for (int q = 0; q < 8; ++q) {
            float4 v = p[q];
            h1r[4 * q + 0] = v.x; h1r[4 * q + 1] = v.y;
            h1r[4 * q + 2] = v.z; h1r[4 * q + 3] = v.w;
        }
    }
    __syncthreads();
    const float* up = Ul[w];
    float acc = 0.f;
    for (int h = 0; h < 31; ++h) {
        float t = 0.f;
#pragma unroll
        for (int g = 0; g < 32; ++g) t += up[h * 32 + g] * h2r[g];
        acc += h1r[h] * t;
    }
    if (o < Cn) sc[(size_t)n * Cn + o] = acc + dbias[o];
}

// ---------------- deprel CE: one wave per n ----------------
__global__ __launch_bounds__(256) void k_drce(const float* __restrict__ sc,
                                              const int* __restrict__ dep_rels,
                                              float* __restrict__ drce_part) {
    int w = threadIdx.x >> 6;
    int l = threadIdx.x & 63;
    int n = blockIdx.x * 4 + w;
    float v = (l < Cn) ? sc[(size_t)n * Cn + l] : NEGV;
    float m = v;
#pragma unroll
    for (int off = 1; off < 64; off <<= 1) m = fmaxf(m, __shfl_xor(m, off));
    float e = (l < Cn) ? __expf(v - m) : 0.f;
#pragma unroll
    for (int off = 1; off < 64; off <<= 1) e += __shfl_xor(e, off);
    float lse = m + __logf(e);
    int r = dep_rels[n]; // uniform per wave
    float vr = __shfl(v, r);
    if (l == 0) drce_part[n] = (r != 0 && r < Cn) ? -(vr - lse) : 0.f;
}

// ---------------- final reduce ----------------
__global__ __launch_bounds__(256) void k_final(const float* __restrict__ un_part,
                                               const float* __restrict__ drce_part,
                                               float* __restrict__ out) {
    __shared__ float red[256];
    int tid = threadIdx.x;
    float a = 0.f;
    for (int idx = tid; idx < Bn * (Wn - 1); idx += 256) a += un_part[idx];
    for (int idx = tid; idx < Bn * Wn; idx += 256) a += drce_part[idx];
    red[tid] = a;
    __syncthreads();
    for (int off = 128; off > 0; off >>= 1) {
        if (tid < off) red[tid] += red[tid + off];
        __syncthreads();
    }
    if (tid == 0) out[0] = red[0];
}

extern "C" void kernel_launch(void* const* d_in, const int* in_sizes, int n_in,
                              void* d_out, int out_size, void* d_ws, size_t ws_size,
                              hipStream_t stream) {
    const float* hiddens = (const float*)d_in[0];
    const int* b2t = (const int*)d_in[1];
    const int* heads = (const int*)d_in[2];
    const int* dep_rels = (const int*)d_in[3];
    const unsigned char* masks = (const unsigned char*)d_in[4];
    const float* Wih_f = (const float*)d_in[6];
    const float* Whh_f = (const float*)d_in[7];
    const float* bih_f = (const float*)d_in[8];
    const float* bhh_f = (const float*)d_in[9];
    const float* Wih_b = (const float*)d_in[10];
    const float* Whh_b = (const float*)d_in[11];
    const float* bih_b = (const float*)d_in[12];
    const float* bhh_b = (const float*)d_in[13];
    const float* un_W1 = (const float*)d_in[14];
    const float* un_b1 = (const float*)d_in[15];
    const float* un_W2 = (const float*)d_in[16];
    const float* un_b2 = (const float*)d_in[17];
    const float* un_U  = (const float*)d_in[18];
    const float* un_bias = (const float*)d_in[19];
    const float* dr_W1 = (const float*)d_in[20];
    const float* dr_b1 = (const float*)d_in[21];
    const float* dr_W2 = (const float*)d_in[22];
    const float* dr_b2 = (const float*)d_in[23];
    const float* dr_U  = (const float*)d_in[24];
    const float* dr_bias = (const float*)d_in[25];

    char* p = (char*)d_ws;
    float* un_part = (float*)p;   p += (size_t)4096 * 4;
    float* drce_part = (float*)p; p += (size_t)4096 * 4;
    int* cnt = (int*)p;           p += (size_t)Bn * Wn * 4;
    int* lists = (int*)p;         p += (size_t)Bn * Wn * CAP * 4;
    float* bert = (float*)p;      p += (size_t)Bn * Wn * Dn * 4;
    float* xg = (float*)p;        p += (size_t)2 * Bn * Wn * 40 * 4;
    float* hs = (float*)p;        p += (size_t)2 * Bn * Wn * Hn * 4;
    float* harr = (float*)p;      p += (size_t)4 * Bn * Wn * 31 * 4;
    float* h1g = (float*)p;       p += (size_t)Bn * Wn * 32 * 4;
    float* h2g = (float*)p;       p += (size_t)Bn * Wn * 32 * 4;
    float* sc = (float*)p;        p += (size_t)Bn * Wn * Cn * 4;

    k_zero<<<(Bn * Wn + 255) / 256, 256, 0, stream>>>(cnt);
    k_lists<<<(Bn * Sn + 255) / 256, 256, 0, stream>>>(b2t, cnt, lists);
    k_bertout<<<Bn * Wn, 192, 0, stream>>>(hiddens, cnt, lists, bert);
    k_xg<<<Bn * 8, 320, 0, stream>>>(bert, Wih_f, bih_f, Wih_b, bih_b, xg);
    k_lstm<<<16, 64, 0, stream>>>(xg, Whh_f, bhh_f, Whh_b, bhh_b, hs);
    k_mlp<<<Bn * Wn, 128, 0, stream>>>(hs, un_W1, un_b1, un_W2, un_b2,
                                       dr_W1, dr_b1, dr_W2, dr_b2, harr, h1g);
    k_gather<<<Bn * Wn * 8 / 256, 256, 0, stream>>>(harr, heads, h2g);
    k_unlab<<<Bn * (Wn - 1), 64, 0, stream>>>(harr, un_U, un_bias, heads, masks, un_part);
    k_drscore<<<13 * 64, 256, 0, stream>>>(h1g, h2g, dr_U, dr_bias, sc);
    k_drce<<<Bn * Wn / 4, 256, 0, stream>>>(sc, dep_rels, drce_part);
    k_final<<<1, 256, 0, stream>>>(un_part, drce_part, (float*)d_out);
}

// Round 5
// 128.897 us; speedup vs baseline: 1.6445x; 1.2693x over previous
//
#include <hip/hip_runtime.h>

#define Bn 32
#define Wn 128
#define Sn 192
#define Dn 768
#define Hn 10
#define BHn 30
#define Cn 50
#define CAP 8
#define NEGV -1e30f
#define XPAD 4

__device__ __forceinline__ float fsig(float x) {
    return __builtin_amdgcn_rcpf(1.0f + __expf(-x));
}
__device__ __forceinline__ float ftanh(float x) {
    return 1.0f - 2.0f * __builtin_amdgcn_rcpf(1.0f + __expf(2.0f * x));
}
__device__ __forceinline__ float lane_bcast(float v, int srclane) {
    union { float f; int i; } u, w;
    u.f = v;
    w.i = __builtin_amdgcn_readlane(u.i, srclane);
    return w.f;
}
template <int Q>
__device__ __forceinline__ float quad_bcast(float v) {
    union { float f; int i; } u, w;
    u.f = v;
    w.i = __builtin_amdgcn_mov_dpp(u.i, (Q << 6) | (Q << 4) | (Q << 2) | Q, 0xf, 0xf, true);
    return w.f;
}

// ---------------- zero counters ----------------
__global__ void k_zero(int* cnt) {
    int i = blockIdx.x * blockDim.x + threadIdx.x;
    if (i < Bn * Wn) cnt[i] = 0;
}

// ---------------- build token->word inverse lists ----------------
__global__ void k_lists(const int* __restrict__ b2t, int* cnt, int* lists) {
    int idx = blockIdx.x * blockDim.x + threadIdx.x;
    if (idx >= Bn * Sn) return;
    int b = idx / Sn;
    int w = b2t[idx];
    if (w < 0 || w >= Wn) return;
    int s = idx % Sn;
    int pos = atomicAdd(&cnt[b * Wn + w], 1);
    if (pos < CAP) lists[(b * Wn + w) * CAP + pos] = s;
}

// ---------------- fused mean(3 layers) + segment-mean ----------------
__global__ __launch_bounds__(192) void k_bertout(const float* __restrict__ hid,
                                                 const int* __restrict__ cnt,
                                                 const int* __restrict__ lists,
                                                 float* __restrict__ bert) {
    int bw = blockIdx.x;  // b*Wn + w
    int d4 = threadIdx.x; // 0..191 (float4 chunks of 768)
    int b = bw / Wn;
    int c = cnt[bw];
    int cc = c < CAP ? c : CAP;
    float4 acc = {0.f, 0.f, 0.f, 0.f};
    for (int tk = 0; tk < cc; ++tk) {
        int s = lists[bw * CAP + tk];
#pragma unroll
        for (int l = 0; l < 3; ++l) {
            const float4* p = (const float4*)(hid + ((size_t)(l * Bn + b) * (Sn + 1) + (s + 1)) * Dn) + d4;
            float4 v = *p;
            acc.x += v.x; acc.y += v.y; acc.z += v.z; acc.w += v.w;
        }
    }
    float inv = 1.0f / (3.0f * (float)(c > 0 ? c : 1));
    acc.x *= inv; acc.y *= inv; acc.z *= inv; acc.w *= inv;
    ((float4*)(bert + (size_t)bw * Dn))[d4] = acc;
}

// ---------------- input-gate projections, TRANSPOSED out: xg[t][j*4+gate] ----------------
__global__ __launch_bounds__(320) void k_xg(const float* __restrict__ bert,
                                            const float* __restrict__ Wf, const float* __restrict__ bf,
                                            const float* __restrict__ Wb, const float* __restrict__ bb,
                                            float* __restrict__ xg) {
    __shared__ float xl[16 * (Dn + XPAD)];
    int b = blockIdx.x >> 3;
    int tc = blockIdx.x & 7;
    int t0 = tc * 16;
    for (int idx = threadIdx.x; idx < 16 * (Dn / 4); idx += 320) {
        int r = idx / (Dn / 4), k4 = idx % (Dn / 4);
        float4 v = ((const float4*)(bert + (size_t)(b * Wn + t0 + r) * Dn))[k4];
        ((float4*)(xl + r * (Dn + XPAD)))[k4] = v;
    }
    __syncthreads();

    int g = threadIdx.x >> 2;  // 0..79
    int tq = threadIdx.x & 3;  // 0..3 -> 4 time rows each
    int dir = g / 40;
    int row = g % 40;          // gate*10 + j
    int off = (row % 10) * 4 + (row / 10); // j*4 + gate
    const float4* wrow = (const float4*)((dir ? Wb : Wf) + row * Dn);
    float bias = (dir ? bb : bf)[row];
    const float4* x0 = (const float4*)(xl + (tq * 4 + 0) * (Dn + XPAD));
    const float4* x1 = (const float4*)(xl + (tq * 4 + 1) * (Dn + XPAD));
    const float4* x2 = (const float4*)(xl + (tq * 4 + 2) * (Dn + XPAD));
    const float4* x3 = (const float4*)(xl + (tq * 4 + 3) * (Dn + XPAD));
    float a0 = 0.f, a1 = 0.f, a2 = 0.f, a3 = 0.f;
    for (int k = 0; k < Dn / 4; ++k) {
        float4 w = wrow[k];
        float4 v0 = x0[k], v1 = x1[k], v2 = x2[k], v3 = x3[k];
        a0 += w.x * v0.x + w.y * v0.y + w.z * v0.z + w.w * v0.w;
        a1 += w.x * v1.x + w.y * v1.y + w.z * v1.z + w.w * v1.w;
        a2 += w.x * v2.x + w.y * v2.y + w.z * v2.z + w.w * v2.w;
        a3 += w.x * v3.x + w.y * v3.y + w.z * v3.z + w.w * v3.w;
    }
    size_t base = (size_t)(dir * Bn + b) * Wn + t0 + tq * 4;
    xg[(base + 0) * 40 + off] = a0 + bias;
    xg[(base + 1) * 40 + off] = a1 + bias;
    xg[(base + 2) * 40 + off] = a2 + bias;
    xg[(base + 3) * 40 + off] = a3 + bias;
}

// ---------------- LSTM scan: 1 seq/wave, readlane h-broadcast, DPP gate combine ----------------
// 64 blocks x 64 threads. lane l<40: j = l>>2, gate = l&3. No LDS anywhere.
__global__ __launch_bounds__(64) void k_lstm(const float* __restrict__ xg,
                                             const float* __restrict__ Whh_f, const float* __restrict__ bhh_f,
                                             const float* __restrict__ Whh_b, const float* __restrict__ bhh_b,
                                             float* __restrict__ hs) {
    int lane = threadIdx.x;
    int seq = blockIdx.x;      // 0..63
    int dir = seq >> 5;
    int l = lane < 40 ? lane : 39;
    int j = l >> 2, G = l & 3;

    const float* Whh = dir ? Whh_b : Whh_f;
    const float* bhh = dir ? bhh_b : bhh_f;
    float wk[Hn];
#pragma unroll
    for (int k = 0; k < Hn; ++k) wk[k] = Whh[(G * Hn + j) * Hn + k];
    float bias = bhh[G * Hn + j];

    const float* xbase = xg + (size_t)seq * Wn * 40; // layout [t][j*4+gate]
    float* hbase = hs + (size_t)seq * Wn * Hn;
    bool st = (G == 0) && (lane < 40);

    float h = 0.f, c = 0.f;
    int dt = dir ? -1 : 1;
    int t = dir ? (Wn - 1) : 0;
    float xq[4];
    // depth-3 register prefetch pipeline; overreads (t+/-3) stay inside ws
    xq[0] = xbase[t * 40 + l];
    xq[1] = xbase[(t + dt) * 40 + l];
    xq[2] = xbase[(t + 2 * dt) * 40 + l];

#pragma unroll 4
    for (int step = 0; step < Wn; ++step) {
        float xv = xq[step & 3];
        xq[(step + 3) & 3] = xbase[(t + 3 * dt) * 40 + l]; // prefetch 3 ahead
        // broadcast h vector from lanes 0,4,...,36 via readlane (no LDS pipe)
        float g = xv;
#pragma unroll
        for (int k = 0; k < Hn; ++k) g += wk[k] * lane_bcast(h, 4 * k);
        g += bias;
        // per-lane activation: sigmoid for i/f/o, tanh for g (tanh(x)=2*sig(2x)-1)
        float gin = (G == 2) ? 2.f * g : g;
        float s = fsig(gin);
        float av = (G == 2) ? 2.f * s - 1.f : s;
        // gather the quad's 4 activated gates via DPP quad-perm broadcast
        float ai = quad_bcast<0>(av);
        float af = quad_bcast<1>(av);
        float ag = quad_bcast<2>(av);
        float ao = quad_bcast<3>(av);
        c = af * c + ai * ag;
        h = ao * ftanh(c);
        if (st) hbase[t * Hn + j] = h;
        t += dt;
    }
}

// ---------------- MLP heads: 4x relu(x@W+b) with appended 1; also writes padded dr-h1 ----------------
__global__ __launch_bounds__(128) void k_mlp(const float* __restrict__ hs,
                                             const float* __restrict__ uW1, const float* __restrict__ ub1,
                                             const float* __restrict__ uW2, const float* __restrict__ ub2,
                                             const float* __restrict__ dW1, const float* __restrict__ db1,
                                             const float* __restrict__ dW2, const float* __restrict__ db2,
                                             float* __restrict__ harr, float* __restrict__ h1g) {
    int bt = blockIdx.x; // b*Wn + t
    int b = bt / Wn, t = bt % Wn;
    __shared__ float x[20];
    int tid = threadIdx.x;
    if (tid < 20) {
        x[tid] = (tid < Hn) ? hs[((size_t)(0 * Bn + b) * Wn + t) * Hn + tid]
                            : hs[((size_t)(1 * Bn + b) * Wn + t) * Hn + (tid - Hn)];
    }
    __syncthreads();
    if (tid == 124) h1g[(size_t)bt * 32 + 31] = 0.f; // pad
    if (tid >= 124) return;
    int which = tid / 31, k = tid % 31;
    float v;
    if (k == 30) {
        v = 1.0f;
    } else {
        const float* Wm;
        const float* bv;
        if (which == 0) { Wm = uW1; bv = ub1; }
        else if (which == 1) { Wm = uW2; bv = ub2; }
        else if (which == 2) { Wm = dW1; bv = db1; }
        else { Wm = dW2; bv = db2; }
        float a = bv[k];
#pragma unroll
        for (int d = 0; d < 20; ++d) a += x[d] * Wm[d * BHn + k];
        v = a > 0.f ? a : 0.f;
    }
    harr[((size_t)which * Bn * Wn + bt) * 31 + k] = v;
    if (which == 2) h1g[(size_t)bt * 32 + k] = v;
}

// ---------------- gather dr-h2 rows at j=head into padded array ----------------
__global__ __launch_bounds__(256) void k_gather(const float* __restrict__ harr,
                                                const int* __restrict__ heads,
                                                float* __restrict__ h2g) {
    int idx = blockIdx.x * 256 + threadIdx.x; // n*8 + q
    int n = idx >> 3, q = idx & 7;
    int b = n >> 7;
    int jh = heads[n];
    if (jh < 0 || jh >= Wn) jh = 0;
    const float* src = harr + ((size_t)3 * Bn * Wn + b * Wn + jh) * 31;
    float4 v;
    float tmp[4];
#pragma unroll
    for (int e = 0; e < 4; ++e) {
        int k = q * 4 + e;
        tmp[e] = (k < 31) ? src[k] : 0.f;
    }
    v.x = tmp[0]; v.y = tmp[1]; v.z = tmp[2]; v.w = tmp[3];
    ((float4*)(h2g + (size_t)n * 32))[q] = v;
}

// ---------------- unlabeled: single-wave per (b,i), shuffle softmax ----------------
__global__ __launch_bounds__(64) void k_unlab(const float* __restrict__ harr,
                                              const float* __restrict__ U0, const float* __restrict__ ubias,
                                              const int* __restrict__ heads, const unsigned char* __restrict__ masks,
                                              float* __restrict__ un_part) {
    int b = blockIdx.x / (Wn - 1);
    int i = 1 + blockIdx.x % (Wn - 1);
    const float* h2a = harr + (size_t)Bn * Wn * 31;
    __shared__ float h2s[Wn * 31];
    __shared__ float U0l[964];
    __shared__ float tgl[31];
    int l = threadIdx.x;
    const float4* src = (const float4*)(h2a + (size_t)b * Wn * 31);
    for (int idx = l; idx < Wn * 31 / 4; idx += 64) ((float4*)h2s)[idx] = src[idx];
    for (int idx = l; idx < 240; idx += 64) ((float4*)U0l)[idx] = ((const float4*)U0)[idx];
    if (l == 0) U0l[960] = U0[960];
    __syncthreads();
    if (l < 31) {
        const float* h1row = harr + ((size_t)b * Wn + i) * 31;
        float a = 0.f;
        for (int h = 0; h < 31; ++h) a += h1row[h] * U0l[h * 31 + l];
        tgl[l] = a;
    }
    __syncthreads();
    float ub = ubias[0];
    float s0 = ub, s1 = ub;
    const float* r0 = h2s + l * 31;
    const float* r1 = h2s + (l + 64) * 31;
#pragma unroll
    for (int g = 0; g < 31; ++g) {
        float tv = tgl[g];
        s0 += tv * r0[g];
        s1 += tv * r1[g];
    }
    if (l == i) s0 = NEGV;
    if (l + 64 == i) s1 = NEGV;
    float m = fmaxf(s0, s1);
#pragma unroll
    for (int off = 1; off < 64; off <<= 1) m = fmaxf(m, __shfl_xor(m, off));
    float e = __expf(s0 - m) + __expf(s1 - m);
#pragma unroll
    for (int off = 1; off < 64; off <<= 1) e += __shfl_xor(e, off);
    float lse = m + __logf(e);
    int head = heads[b * Wn + i]; // uniform
    float v = (head < 64) ? s0 : s1;
    float sh = __shfl(v, head & 63);
    if (l == 0) un_part[blockIdx.x] = masks[b * Wn + i] ? 0.f : -(sh - lse);
}

// ---------------- deprel scores: thread=(n,o), U broadcast from LDS, h1/h2 in regs ----------------
__global__ __launch_bounds__(256) void k_drscore(const float* __restrict__ h1g,
                                                 const float* __restrict__ h2g,
                                                 const float* __restrict__ U, const float* __restrict__ dbias,
                                                 float* __restrict__ sc) {
    int nc = blockIdx.x & 63;
    int oq = blockIdx.x >> 6; // 0..12
    __shared__ float Ul[4][992]; // row stride 32 per h (aligned b128)
    int tid = threadIdx.x;
    for (int idx = tid; idx < 4 * 992; idx += 256) {
        int o = idx / 992, r = idx - o * 992;
        int h = r >> 5, g = r & 31;
        int oo = oq * 4 + o; if (oo >= Cn) oo = Cn - 1;
        Ul[o][r] = (g < 31) ? U[(size_t)oo * 961 + h * 31 + g] : 0.f;
    }
    int w = tid >> 6, lane = tid & 63;
    int o = oq * 4 + w;
    int n = nc * 64 + lane;
    float h2r[32];
    {
        const float4* p = (const float4*)(h2g + (size_t)n * 32);
#pragma unroll
        for (int q = 0; q < 8; ++q) {
            float4 v = p[q];
            h2r[4 * q + 0] = v.x; h2r[4 * q + 1] = v.y;
            h2r[4 * q + 2] = v.z; h2r[4 * q + 3] = v.w;
        }
    }
    float h1r[32];
    {
        const float4* p = (const float4*)(h1g + (size_t)n * 32);
#pragma unroll
        for (int q = 0; q < 8; ++q) {
            float4 v = p[q];
            h1r[4 * q + 0] = v.x; h1r[4 * q + 1] = v.y;
            h1r[4 * q + 2] = v.z; h1r[4 * q + 3] = v.w;
        }
    }
    __syncthreads();
    const float* up = Ul[w];
    float acc = 0.f;
    for (int h = 0; h < 31; ++h) {
        float t = 0.f;
#pragma unroll
        for (int g = 0; g < 32; ++g) t += up[h * 32 + g] * h2r[g];
        acc += h1r[h] * t;
    }
    if (o < Cn) sc[(size_t)n * Cn + o] = acc + dbias[o];
}

// ---------------- deprel CE: one wave per n ----------------
__global__ __launch_bounds__(256) void k_drce(const float* __restrict__ sc,
                                              const int* __restrict__ dep_rels,
                                              float* __restrict__ drce_part) {
    int w = threadIdx.x >> 6;
    int l = threadIdx.x & 63;
    int n = blockIdx.x * 4 + w;
    float v = (l < Cn) ? sc[(size_t)n * Cn + l] : NEGV;
    float m = v;
#pragma unroll
    for (int off = 1; off < 64; off <<= 1) m = fmaxf(m, __shfl_xor(m, off));
    float e = (l < Cn) ? __expf(v - m) : 0.f;
#pragma unroll
    for (int off = 1; off < 64; off <<= 1) e += __shfl_xor(e, off);
    float lse = m + __logf(e);
    int r = dep_rels[n]; // uniform per wave
    float vr = __shfl(v, r);
    if (l == 0) drce_part[n] = (r != 0 && r < Cn) ? -(vr - lse) : 0.f;
}

// ---------------- final reduce ----------------
__global__ __launch_bounds__(256) void k_final(const float* __restrict__ un_part,
                                               const float* __restrict__ drce_part,
                                               float* __restrict__ out) {
    __shared__ float red[256];
    int tid = threadIdx.x;
    float a = 0.f;
    for (int idx = tid; idx < Bn * (Wn - 1); idx += 256) a += un_part[idx];
    for (int idx = tid; idx < Bn * Wn; idx += 256) a += drce_part[idx];
    red[tid] = a;
    __syncthreads();
    for (int off = 128; off > 0; off >>= 1) {
        if (tid < off) red[tid] += red[tid + off];
        __syncthreads();
    }
    if (tid == 0) out[0] = red[0];
}

extern "C" void kernel_launch(void* const* d_in, const int* in_sizes, int n_in,
                              void* d_out, int out_size, void* d_ws, size_t ws_size,
                              hipStream_t stream) {
    const float* hiddens = (const float*)d_in[0];
    const int* b2t = (const int*)d_in[1];
    const int* heads = (const int*)d_in[2];
    const int* dep_rels = (const int*)d_in[3];
    const unsigned char* masks = (const unsigned char*)d_in[4];
    const float* Wih_f = (const float*)d_in[6];
    const float* Whh_f = (const float*)d_in[7];
    const float* bih_f = (const float*)d_in[8];
    const float* bhh_f = (const float*)d_in[9];
    const float* Wih_b = (const float*)d_in[10];
    const float* Whh_b = (const float*)d_in[11];
    const float* bih_b = (const float*)d_in[12];
    const float* bhh_b = (const float*)d_in[13];
    const float* un_W1 = (const float*)d_in[14];
    const float* un_b1 = (const float*)d_in[15];
    const float* un_W2 = (const float*)d_in[16];
    const float* un_b2 = (const float*)d_in[17];
    const float* un_U  = (const float*)d_in[18];
    const float* un_bias = (const float*)d_in[19];
    const float* dr_W1 = (const float*)d_in[20];
    const float* dr_b1 = (const float*)d_in[21];
    const float* dr_W2 = (const float*)d_in[22];
    const float* dr_b2 = (const float*)d_in[23];
    const float* dr_U  = (const float*)d_in[24];
    const float* dr_bias = (const float*)d_in[25];

    char* p = (char*)d_ws;
    float* un_part = (float*)p;   p += (size_t)4096 * 4;
    float* drce_part = (float*)p; p += (size_t)4096 * 4;
    int* cnt = (int*)p;           p += (size_t)Bn * Wn * 4;
    int* lists = (int*)p;         p += (size_t)Bn * Wn * CAP * 4;
    float* bert = (float*)p;      p += (size_t)Bn * Wn * Dn * 4;
    float* xg = (float*)p;        p += (size_t)2 * Bn * Wn * 40 * 4;
    float* hs = (float*)p;        p += (size_t)2 * Bn * Wn * Hn * 4;
    float* harr = (float*)p;      p += (size_t)4 * Bn * Wn * 31 * 4;
    float* h1g = (float*)p;       p += (size_t)Bn * Wn * 32 * 4;
    float* h2g = (float*)p;       p += (size_t)Bn * Wn * 32 * 4;
    float* sc = (float*)p;        p += (size_t)Bn * Wn * Cn * 4;

    k_zero<<<(Bn * Wn + 255) / 256, 256, 0, stream>>>(cnt);
    k_lists<<<(Bn * Sn + 255) / 256, 256, 0, stream>>>(b2t, cnt, lists);
    k_bertout<<<Bn * Wn, 192, 0, stream>>>(hiddens, cnt, lists, bert);
    k_xg<<<Bn * 8, 320, 0, stream>>>(bert, Wih_f, bih_f, Wih_b, bih_b, xg);
    k_lstm<<<64, 64, 0, stream>>>(xg, Whh_f, bhh_f, Whh_b, bhh_b, hs);
    k_mlp<<<Bn * Wn, 128, 0, stream>>>(hs, un_W1, un_b1, un_W2, un_b2,
                                       dr_W1, dr_b1, dr_W2, dr_b2, harr, h1g);
    k_gather<<<Bn * Wn * 8 / 256, 256, 0, stream>>>(harr, heads, h2g);
    k_unlab<<<Bn * (Wn - 1), 64, 0, stream>>>(harr, un_U, un_bias, heads, masks, un_part);
    k_drscore<<<13 * 64, 256, 0, stream>>>(h1g, h2g, dr_U, dr_bias, sc);
    k_drce<<<Bn * Wn / 4, 256, 0, stream>>>(sc, dep_rels, drce_part);
    k_final<<<1, 256, 0, stream>>>(un_part, drce_part, (float*)d_out);
}